// Round 10
// baseline (850.810 us; speedup 1.0000x reference)
//
#include <hip/hip_runtime.h>
#include <math.h>
#include <stdint.h>

#define D 128
#define EPS 1e-6f
typedef unsigned short u16;

// ---------------------------------------------------------------------------
// state layout (floats), 16B-aligned base:
//   st[0..127]   : q
//   st[128..255] : q_plus
//   st[256..383] : hop accumulator (device atomicAdd targets)
//   st[384]      : ||q||   st[385] : ||q_plus||   st[386] : sum-of-exp
// Rules learned: no device fences after bulk writes (r6, ~100us); no global
// atomic scatters (r8, ~84ns/atomic); gather time = TCC bytes / 3.8 TB/s (r9)
// -> this round: channel-sliced passes keep the 3.2MB table slice L2-resident.
// ---------------------------------------------------------------------------

__device__ __forceinline__ float wave_sum(float v) {
#pragma unroll
    for (int off = 32; off > 0; off >>= 1) v += __shfl_xor(v, off, 64);
    return v;
}
__device__ __forceinline__ float halfwave_sum(float v) {
#pragma unroll
    for (int off = 16; off > 0; off >>= 1) v += __shfl_xor(v, off, 32);
    return v;
}
__device__ __forceinline__ float quarter_sum(float v) {
#pragma unroll
    for (int off = 8; off > 0; off >>= 1) v += __shfl_xor(v, off, 16);
    return v;
}

__device__ __forceinline__ float bf2f(u16 h) {
    union { unsigned u; float f; } x;
    x.u = ((unsigned)h) << 16;
    return x.f;
}
__device__ __forceinline__ float bflo(unsigned u) { return bf2f((u16)(u & 0xffff)); }
__device__ __forceinline__ float bfhi(unsigned u) { return bf2f((u16)(u >> 16)); }
__device__ __forceinline__ u16 f2bf(float f) {  // round-to-nearest-even
    union { float f; unsigned u; } x;
    x.f = f;
    unsigned u = x.u;
    return (u16)((u + 0x7fff + ((u >> 16) & 1)) >> 16);
}
__device__ __forceinline__ unsigned pack2(float a, float b) {
    return (unsigned)f2bf(a) | ((unsigned)f2bf(b) << 16);
}

// ===========================================================================
// K1: fp32 table -> bf16 SLICE-MAJOR layout. Slice s (32 channels) of row v
// lives at dst[(s*V + v)*32 ...], contiguous 3.2MB per slice.
// ===========================================================================
__global__ void table_to_bf16_s(const float* __restrict__ src,
                                u16* __restrict__ dst, int V) {
    int i = blockIdx.x * blockDim.x + threadIdx.x;  // over V*64 channel-pairs
    if (i < V * 64) {
        int v = i >> 6;
        int c2 = i & 63;  // channel pair index, ch = 2*c2
        float a = src[(long)v * D + 2 * c2];
        float b = src[(long)v * D + 2 * c2 + 1];
        int s = c2 >> 4;       // slice
        int p = c2 & 15;       // pair within slice
        *(unsigned*)(dst + ((long)s * V + v) * 32 + 2 * p) = pack2(a, b);
    }
}

// ===========================================================================
// K2 (x4): one slice pass. Quarter-wave (16 lanes) owns a row; lane loads
// uint (2 channels) from the L2-resident 3.2MB slice. Gathers k (norm partial)
// and v (store vb slice-major). kb never stored: dots come via linearity.
// pass==0 initializes knp; pass==3 finishes sqrt -> knp holds knorms.
// ===========================================================================
template <int L>  // L == 20
__global__ void kv_slice_pass(const u16* __restrict__ tslice,
                              const int* __restrict__ kids,
                              const int* __restrict__ vids, int N,
                              u16* __restrict__ vb_slice,
                              float* __restrict__ knp, int pass) {
    const int lane = threadIdx.x & 63;
    const int q = lane >> 4;   // row within group
    const int ql = lane & 15;  // lane within quarter: channel pair 2*ql
    int gw = (int)((blockIdx.x * blockDim.x + threadIdx.x) >> 6);
    int nw = (int)((gridDim.x * blockDim.x) >> 6);
    const int ngroup = N >> 2;
    for (int g = gw; g < ngroup; g += nw) {
        const long ibase = (long)g * (4 * L);
        int kidA = kids[ibase + lane];
        int vidA = vids[ibase + lane];
        int kidB = (lane < 4 * L - 64) ? kids[ibase + 64 + lane] : 0;
        int vidB = (lane < 4 * L - 64) ? vids[ibase + 64 + lane] : 0;
        float k0 = 0.f, k1 = 0.f, v0 = 0.f, v1 = 0.f;
#pragma unroll
        for (int t = 0; t < L; ++t) {
            const int j = L * q + t;
            const int jb = j - 64;
            int kA = __shfl(kidA, j & 63, 64);
            int kB = __shfl(kidB, jb < 0 ? 0 : jb, 64);
            int vA = __shfl(vidA, j & 63, 64);
            int vB = __shfl(vidB, jb < 0 ? 0 : jb, 64);
            const int kj = (j < 64) ? kA : kB;
            const int vj = (j < 64) ? vA : vB;
            const unsigned ke = *(const unsigned*)(tslice + (long)kj * 32 + 2 * ql);
            const unsigned ve = *(const unsigned*)(tslice + (long)vj * 32 + 2 * ql);
            k0 += bflo(ke); k1 += bfhi(ke);
            v0 += bflo(ve); v1 += bfhi(ve);
        }
        const int row = 4 * g + q;
        *(unsigned*)(vb_slice + (long)row * 32 + 2 * ql) = pack2(v0, v1);
        float sq = quarter_sum(k0 * k0 + k1 * k1);
        if (ql == 0) {
            if (pass == 0) knp[row] = sq;
            else if (pass == 3) knp[row] = sqrtf(knp[row] + sq);
            else knp[row] += sq;
        }
    }
}

// ===========================================================================
// A2: s[v] = T16[v] . q_plus (slice-major read; lane covers ch 2*lane,2*lane+1)
// ===========================================================================
__global__ void a2_s(const u16* __restrict__ tbl_s, const float* __restrict__ st,
                     float* __restrict__ s, int V) {
    const int lane = threadIdx.x & 63;
    const int q = lane >> 4;
    const int ql = lane & 15;
    const float2 qp2 = *(const float2*)(st + 128 + 2 * lane);
    int gw = (int)((blockIdx.x * blockDim.x + threadIdx.x) >> 6);
    int nw = (int)((gridDim.x * blockDim.x) >> 6);
    for (int v = gw; v < V; v += nw) {
        const unsigned u = *(const unsigned*)(tbl_s + ((long)q * V + v) * 32 + 2 * ql);
        float d = bflo(u) * qp2.x + bfhi(u) * qp2.y;
        d = wave_sum(d);
        if (lane == 0) s[v] = d;
    }
}

// ===========================================================================
// B2: per row: dot = sum_t s[kid], e = exp(dot/(knorm*|qp|)), store e[row],
// block-reduce esum -> st[386]. No scatter (r8 lesson).
// ===========================================================================
__global__ void b2e(const float* __restrict__ s, const int* __restrict__ kids,
                    const float* __restrict__ knorms, const float* __restrict__ st,
                    float* __restrict__ e, int N) {
    __shared__ float se[4];
    const int tid = threadIdx.x;
    const int row = blockIdx.x * blockDim.x + tid;
    const float qpn = st[385];
    float ev = 0.f;
    if (row < N) {
        const int4* kp = (const int4*)(kids + (long)row * 20);
        int4 k0 = kp[0], k1 = kp[1], k2 = kp[2], k3 = kp[3], k4 = kp[4];
        float dot = s[k0.x] + s[k0.y] + s[k0.z] + s[k0.w] +
                    s[k1.x] + s[k1.y] + s[k1.z] + s[k1.w] +
                    s[k2.x] + s[k2.y] + s[k2.z] + s[k2.w] +
                    s[k3.x] + s[k3.y] + s[k3.z] + s[k3.w] +
                    s[k4.x] + s[k4.y] + s[k4.z] + s[k4.w];
        const float c = dot / fmaxf(knorms[row] * qpn, EPS);
        ev = __expf(c);
        e[row] = ev;
    }
    float et = wave_sum(ev);
    if ((tid & 63) == 0) se[tid >> 6] = et;
    __syncthreads();
    if (tid == 0) atomicAdd((float*)&st[386], se[0] + se[1] + se[2] + se[3]);
}

// ===========================================================================
// CV: st[256..383] += sum_i e[i] * vb16[i]. Half-wave per row; lane hl reads
// 8B of slice hl>>3 (slice-major), channels 32*(hl>>3)+4*(hl&7)+0..3.
// ===========================================================================
__global__ void cv_acc(const u16* __restrict__ vb, const float* __restrict__ e,
                       float* __restrict__ st, int N) {
    __shared__ float acc_s[128];
    const int tid = threadIdx.x;
    const int lane = tid & 63;
    const int half = lane >> 5;
    const int hl = lane & 31;
    const int s4 = hl >> 3;
    const int w8 = hl & 7;
    int gw = (int)((blockIdx.x * blockDim.x + tid) >> 6);
    int nw = (int)((gridDim.x * blockDim.x) >> 6);
    float4 acc = {0.f, 0.f, 0.f, 0.f};
    const int npair = N >> 1;
    for (int p = gw; p < npair; p += nw) {
        const int i = 2 * p + half;
        float ei = e[i];  // same per half-wave; each lane loads (L2-hit)
        const ushort4 vh = *(const ushort4*)(vb + ((long)s4 * N + i) * 32 + 4 * w8);
        acc.x += ei * bf2f(vh.x);
        acc.y += ei * bf2f(vh.y);
        acc.z += ei * bf2f(vh.z);
        acc.w += ei * bf2f(vh.w);
    }
    // merge halves (identical channel mapping)
    acc.x += __shfl_xor(acc.x, 32, 64);
    acc.y += __shfl_xor(acc.y, 32, 64);
    acc.z += __shfl_xor(acc.z, 32, 64);
    acc.w += __shfl_xor(acc.w, 32, 64);
    if (tid < 128) acc_s[tid] = 0.f;
    __syncthreads();
    const int ch = 32 * s4 + 4 * w8;
    if (half == 0) {
        atomicAdd(&acc_s[ch + 0], acc.x);
        atomicAdd(&acc_s[ch + 1], acc.y);
        atomicAdd(&acc_s[ch + 2], acc.z);
        atomicAdd(&acc_s[ch + 3], acc.w);
    }
    __syncthreads();
    if (tid < 128) atomicAdd(&st[256 + tid], acc_s[tid]);
}

// ===========================================================================
// Small fp32 encodes: persona rows + q, one block.
// ===========================================================================
__global__ void encode_small(const float* __restrict__ emb,
                             const int* __restrict__ pers, int NP, int LP,
                             const int* __restrict__ xs, int LQ,
                             float* __restrict__ pers_rows,
                             float* __restrict__ pnorms,
                             float* __restrict__ st) {
    int lane = threadIdx.x & 63;
    int w = threadIdx.x >> 6;
    for (int i = w; i <= NP; i += 4) {
        const int* ids;
        int L;
        float* out;
        float* nrm;
        if (i < NP) { ids = pers + (long)i * LP; L = LP; out = pers_rows + (long)i * D; nrm = pnorms + i; }
        else        { ids = xs; L = LQ; out = st; nrm = st + 384; }
        float2 acc = {0.f, 0.f};
        for (int t = 0; t < L; ++t) {
            int idx = ids[t];
            const float2 e = *(const float2*)(emb + (long)idx * D + 2 * lane);
            acc.x += e.x;
            acc.y += e.y;
        }
        *(float2*)(out + 2 * lane) = acc;
        float sq = wave_sum(acc.x * acc.x + acc.y * acc.y);
        if (lane == 0) *nrm = sqrtf(sq);
    }
}

// ===========================================================================
// Hop kernels (1 block, 128 threads) — known-good since r3.
// ===========================================================================
__global__ void persona_hop(const float* __restrict__ pers_rows,
                            const float* __restrict__ pnorms,
                            const float* __restrict__ W,
                            float* __restrict__ st, int NP) {
    __shared__ float qsh[D];
    __shared__ float att[64];
    __shared__ float qh[D];
    __shared__ float red[2];
    int tid = threadIdx.x;
    qsh[tid] = st[tid];
    __syncthreads();
    if (tid < NP) {
        float dot = 0.f;
        for (int d2 = 0; d2 < D; ++d2) dot += pers_rows[tid * D + d2] * qsh[d2];
        att[tid] = dot / fmaxf(pnorms[tid] * st[384], EPS);
    }
    __syncthreads();
    if (tid == 0) {
        float m = -1e30f;
        for (int p = 0; p < NP; ++p) m = fmaxf(m, att[p]);
        float s = 0.f;
        for (int p = 0; p < NP; ++p) { att[p] = __expf(att[p] - m); s += att[p]; }
        float inv = 1.f / s;
        for (int p = 0; p < NP; ++p) att[p] *= inv;
    }
    __syncthreads();
    float h = 0.f;
    for (int p = 0; p < NP; ++p) h += att[p] * pers_rows[p * D + tid];
    qh[tid] = qsh[tid] + h;
    __syncthreads();
    float qp = 0.f;
    for (int d2 = 0; d2 < D; ++d2) qp += W[tid * D + d2] * qh[d2];
    st[128 + tid] = qp;
    float sq = wave_sum(qp * qp);
    if ((tid & 63) == 0) red[tid >> 6] = sq;
    __syncthreads();
    if (tid == 0) st[385] = sqrtf(red[0] + red[1]);
    st[256 + tid] = 0.f;
    if (tid == 0) st[386] = 0.f;
}

__global__ void mid_hop(const float* __restrict__ W1, const float* __restrict__ W2,
                        const float* __restrict__ pers_rows,
                        const float* __restrict__ pnorms,
                        float* __restrict__ st, int NP) {
    __shared__ float qh[D];
    __shared__ float qsh[D];
    __shared__ float att[64];
    __shared__ float red[2];
    int tid = threadIdx.x;
    float inv = 1.f / st[386];
    qh[tid] = st[128 + tid] + st[256 + tid] * inv;
    __syncthreads();
    float qn = 0.f;
    for (int d2 = 0; d2 < D; ++d2) qn += W1[tid * D + d2] * qh[d2];
    qsh[tid] = qn;
    st[tid] = qn;
    float sq = wave_sum(qn * qn);
    if ((tid & 63) == 0) red[tid >> 6] = sq;
    __syncthreads();
    float qnorm = sqrtf(red[0] + red[1]);
    if (tid == 0) st[384] = qnorm;
    if (tid < NP) {
        float dot = 0.f;
        for (int d2 = 0; d2 < D; ++d2) dot += pers_rows[tid * D + d2] * qsh[d2];
        att[tid] = dot / fmaxf(pnorms[tid] * qnorm, EPS);
    }
    __syncthreads();
    if (tid == 0) {
        float m = -1e30f;
        for (int p = 0; p < NP; ++p) m = fmaxf(m, att[p]);
        float s = 0.f;
        for (int p = 0; p < NP; ++p) { att[p] = __expf(att[p] - m); s += att[p]; }
        float is = 1.f / s;
        for (int p = 0; p < NP; ++p) att[p] *= is;
    }
    __syncthreads();
    float h = 0.f;
    for (int p = 0; p < NP; ++p) h += att[p] * pers_rows[p * D + tid];
    qh[tid] = qsh[tid] + h;
    __syncthreads();
    float qp = 0.f;
    for (int d2 = 0; d2 < D; ++d2) qp += W2[tid * D + d2] * qh[d2];
    st[128 + tid] = qp;
    float sq2 = wave_sum(qp * qp);
    if ((tid & 63) == 0) red[tid >> 6] = sq2;
    __syncthreads();
    if (tid == 0) st[385] = sqrtf(red[0] + red[1]);
    st[256 + tid] = 0.f;
    if (tid == 0) st[386] = 0.f;
}

__global__ void finish_hop(const float* __restrict__ W, float* __restrict__ st) {
    __shared__ float qh[D];
    __shared__ float red[2];
    int tid = threadIdx.x;
    float inv = 1.f / st[386];
    qh[tid] = st[128 + tid] + st[256 + tid] * inv;
    __syncthreads();
    float qn = 0.f;
    for (int d2 = 0; d2 < D; ++d2) qn += W[tid * D + d2] * qh[d2];
    st[tid] = qn;
    float sq = wave_sum(qn * qn);
    if ((tid & 63) == 0) red[tid >> 6] = sq;
    __syncthreads();
    if (tid == 0) st[384] = sqrtf(red[0] + red[1]);
}

// ===========================================================================
// K5: candidate gather + cosine, fused.
// ===========================================================================
__global__ void k5_final(const float* __restrict__ cemb,
                         const int* __restrict__ cands, int NC,
                         const float* __restrict__ st, float* __restrict__ out) {
    const int lane = threadIdx.x & 63;
    const int half = lane >> 5;
    const int hl = lane & 31;
    const int gw = (int)((blockIdx.x * blockDim.x + threadIdx.x) >> 6);
    const int nw = (int)((gridDim.x * blockDim.x) >> 6);
    const float4 q4 = *(const float4*)(st + 4 * hl);
    const float qn = st[384];
    const int npair = (NC + 1) >> 1;
    for (int p = gw; p < npair; p += nw) {
        const int row = 2 * p + half;
        const bool valid = row < NC;
        const int rowc = valid ? row : (NC - 1);
        int myid = 0;
        if (hl < 20) myid = cands[(long)rowc * 20 + hl];
        float4 acc = {0.f, 0.f, 0.f, 0.f};
#pragma unroll
        for (int t = 0; t < 20; ++t) {
            const int idx = __shfl(myid, (half << 5) + t, 64);
            const float4 e = *(const float4*)(cemb + (long)idx * D + 4 * hl);
            acc.x += e.x; acc.y += e.y; acc.z += e.z; acc.w += e.w;
        }
        float dot = halfwave_sum(acc.x * q4.x + acc.y * q4.y +
                                 acc.z * q4.z + acc.w * q4.w);
        float nsq = halfwave_sum(acc.x * acc.x + acc.y * acc.y +
                                 acc.z * acc.z + acc.w * acc.w);
        if (valid && hl == 0) out[row] = dot / fmaxf(sqrtf(nsq) * qn, EPS);
    }
}

// ===========================================================================
// Fallback big attention: fp32 on-the-fly gather (workspace too small).
// ===========================================================================
__global__ void big_att_rc(const float* __restrict__ emb,
                           const int* __restrict__ kids,
                           const int* __restrict__ vids,
                           float* __restrict__ st, int N) {
    __shared__ float s[129];
    const int tid = threadIdx.x;
    const int lane = tid & 63;
    const int half = lane >> 5;
    const int hl = lane & 31;
    const int gw = (int)((blockIdx.x * blockDim.x + tid) >> 6);
    const int nw = (int)((gridDim.x * blockDim.x) >> 6);
    const float4 qp = *(const float4*)(st + 128 + 4 * hl);
    const float qpn = st[385];
    float4 hacc = {0.f, 0.f, 0.f, 0.f};
    float esum = 0.f;
    const int npair = (N + 1) >> 1;
    for (int p = gw; p < npair; p += nw) {
        const int row = 2 * p + half;
        const bool valid = row < N;
        const int rowc = valid ? row : (N - 1);
        int kid = 0, vid = 0;
        if (hl < 20) {
            kid = kids[(long)rowc * 20 + hl];
            vid = vids[(long)rowc * 20 + hl];
        }
        float4 ka = {0.f, 0.f, 0.f, 0.f}, va = {0.f, 0.f, 0.f, 0.f};
#pragma unroll
        for (int t = 0; t < 20; ++t) {
            const int ki = __shfl(kid, (half << 5) + t, 64);
            const int vi = __shfl(vid, (half << 5) + t, 64);
            const float4 ke = *(const float4*)(emb + (long)ki * D + 4 * hl);
            const float4 ve = *(const float4*)(emb + (long)vi * D + 4 * hl);
            ka.x += ke.x; ka.y += ke.y; ka.z += ke.z; ka.w += ke.w;
            va.x += ve.x; va.y += ve.y; va.z += ve.z; va.w += ve.w;
        }
        float nsq = halfwave_sum(ka.x * ka.x + ka.y * ka.y + ka.z * ka.z + ka.w * ka.w);
        float dot = halfwave_sum(ka.x * qp.x + ka.y * qp.y + ka.z * qp.z + ka.w * qp.w);
        const float c = dot / fmaxf(sqrtf(nsq) * qpn, EPS);
        float e = __expf(c);
        if (!valid) e = 0.f;
        hacc.x += e * va.x; hacc.y += e * va.y;
        hacc.z += e * va.z; hacc.w += e * va.w;
        if (hl == 0) esum += e;
    }
    hacc.x += __shfl_xor(hacc.x, 32, 64);
    hacc.y += __shfl_xor(hacc.y, 32, 64);
    hacc.z += __shfl_xor(hacc.z, 32, 64);
    hacc.w += __shfl_xor(hacc.w, 32, 64);
    esum += __shfl_xor(esum, 32, 64);
    if (tid < 129) s[tid] = 0.f;
    __syncthreads();
    if (half == 0) {
        atomicAdd(&s[4 * hl + 0], hacc.x);
        atomicAdd(&s[4 * hl + 1], hacc.y);
        atomicAdd(&s[4 * hl + 2], hacc.z);
        atomicAdd(&s[4 * hl + 3], hacc.w);
        if (hl == 0) atomicAdd(&s[128], esum);
    }
    __syncthreads();
    if (tid < 128) atomicAdd(&st[256 + tid], s[tid]);
    if (tid == 128) atomicAdd(&st[386], s[128]);
}

static inline size_t align16(size_t b) { return (b + 15) & ~(size_t)15; }

extern "C" void kernel_launch(void* const* d_in, const int* in_sizes, int n_in,
                              void* d_out, int out_size, void* d_ws, size_t ws_size,
                              hipStream_t stream) {
    const int* xs = (const int*)d_in[0];
    const int* cands = (const int*)d_in[1];
    const int* pers = (const int*)d_in[2];
    const int* keys = (const int*)d_in[3];
    const int* values = (const int*)d_in[4];
    const float* semb = (const float*)d_in[6];
    const float* cemb = (const float*)d_in[7];
    const float* RW = (const float*)d_in[8];
    const float* R2W = (const float*)d_in[9];
    float* out = (float*)d_out;

    const int L = 20;
    const int LQ = in_sizes[0];
    const int VD = in_sizes[6];         // V*D
    const int V = VD / D;               // 50000
    const int NMEM = in_sizes[3] / L;   // 65536
    const int NCAND = in_sizes[1] / L;  // 10000
    const int NPERS = in_sizes[2] / L;  // 20

    size_t need = align16((size_t)VD * 2) + align16((size_t)NMEM * D * 2) +
                  align16((size_t)NMEM * 4) * 2 + align16((size_t)V * 4) +
                  align16((size_t)NPERS * D * 4) + align16((size_t)NPERS * 4) +
                  512 * 4;
    bool stored = (d_ws != nullptr) && (ws_size >= need) && (NMEM % 4 == 0) &&
                  ((VD & 3) == 0);

    const int THR = 256;
    char* base = (char*)d_ws;
    u16 *tbl16s = nullptr, *vb = nullptr;
    float *knp = nullptr, *sv = nullptr, *ev = nullptr;
    if (stored) {
        tbl16s = (u16*)base; base += align16((size_t)VD * 2);        // slice-major
        vb = (u16*)base;     base += align16((size_t)NMEM * D * 2);  // slice-major
        knp = (float*)base;  base += align16((size_t)NMEM * 4);      // -> knorms
        ev = (float*)base;   base += align16((size_t)NMEM * 4);
        sv = (float*)base;   base += align16((size_t)V * 4);
    }
    float* enc_pers = (float*)base; base += align16((size_t)NPERS * D * 4);
    float* pnorms = (float*)base;   base += align16((size_t)NPERS * 4);
    float* st = (float*)base;

    if (stored) {
        // K1: slice-major bf16 conversion
        {
            int n = V * 64;
            table_to_bf16_s<<<(n + THR - 1) / THR, THR, 0, stream>>>(semb, tbl16s, V);
        }
        // K2 x4: slice passes (gather k->norm partials, v->vb; L2-resident slice)
        {
            int ngroup = NMEM / 4;          // 1 group per wave
            int blocks = (ngroup + 3) / 4;  // 4 waves/block
            for (int s = 0; s < 4; ++s) {
                kv_slice_pass<20><<<blocks, THR, 0, stream>>>(
                    tbl16s + (size_t)s * V * 32, keys, values, NMEM,
                    vb + (size_t)s * NMEM * 32, knp, s);
            }
        }
        // small encodes + persona hop 1 (zeroes acc/esum)
        encode_small<<<1, THR, 0, stream>>>(semb, pers, NPERS, L, xs, LQ,
                                            enc_pers, pnorms, st);
        persona_hop<<<1, 128, 0, stream>>>(enc_pers, pnorms, RW, st, NPERS);
        // hop 1: s = T.q_plus ; e per row ; acc += e*v
        a2_s<<<(V + 3) / 4, THR, 0, stream>>>(tbl16s, st, sv, V);
        b2e<<<NMEM / THR, THR, 0, stream>>>(sv, keys, knp, st, ev, NMEM);
        cv_acc<<<(NMEM / 2 + 3) / 4, THR, 0, stream>>>(vb, ev, st, NMEM);
        mid_hop<<<1, 128, 0, stream>>>(RW, R2W, enc_pers, pnorms, st, NPERS);
        // hop 2
        a2_s<<<(V + 3) / 4, THR, 0, stream>>>(tbl16s, st, sv, V);
        b2e<<<NMEM / THR, THR, 0, stream>>>(sv, keys, knp, st, ev, NMEM);
        cv_acc<<<(NMEM / 2 + 3) / 4, THR, 0, stream>>>(vb, ev, st, NMEM);
        finish_hop<<<1, 128, 0, stream>>>(R2W, st);
        // final: fused candidate gather + cosine
        int nblk5 = (((NCAND + 1) / 2) + 3) / 4;
        k5_final<<<nblk5, THR, 0, stream>>>(cemb, cands, NCAND, st, out);
        (void)n_in; (void)out_size;
        return;
    }

    // -------- fallback: fp32 on-the-fly gather --------
    encode_small<<<1, THR, 0, stream>>>(semb, pers, NPERS, L, xs, LQ,
                                        enc_pers, pnorms, st);
    persona_hop<<<1, 128, 0, stream>>>(enc_pers, pnorms, RW, st, NPERS);
    big_att_rc<<<1024, THR, 0, stream>>>(semb, keys, values, st, NMEM);
    mid_hop<<<1, 128, 0, stream>>>(RW, R2W, enc_pers, pnorms, st, NPERS);
    big_att_rc<<<1024, THR, 0, stream>>>(semb, keys, values, st, NMEM);
    finish_hop<<<1, 128, 0, stream>>>(R2W, st);
    int nblk5 = (((NCAND + 1) / 2) + 3) / 4;
    k5_final<<<nblk5, THR, 0, stream>>>(cemb, cands, NCAND, st, out);

    (void)n_in; (void)out_size;
}

// Round 11
// 387.575 us; speedup vs baseline: 2.1952x; 2.1952x over previous
//
#include <hip/hip_runtime.h>
#include <math.h>
#include <stdint.h>

#define D 128
#define EPS 1e-6f
typedef unsigned short u16;

// ---------------------------------------------------------------------------
// state layout (floats), 16B-aligned base:
//   st[0..127]   : q
//   st[128..255] : q_plus
//   st[256..383] : hop accumulator (device atomicAdd targets)
//   st[384]      : ||q||   st[385] : ||q_plus||   st[386] : sum-of-exp
// Rules learned: no device fences after bulk writes (r6, ~100us); no global
// atomic scatters (r8, ~84ns/atomic); gather time ~= TCC bytes / 3.8 TB/s
// (r9); reducer grids <= 1024 blocks or the final-atomic tail serializes
// (r10: 8192-block cv_acc = 266us of atomics; 1024-block r7 twin was ~10us).
// ---------------------------------------------------------------------------

__device__ __forceinline__ float wave_sum(float v) {
#pragma unroll
    for (int off = 32; off > 0; off >>= 1) v += __shfl_xor(v, off, 64);
    return v;
}
__device__ __forceinline__ float halfwave_sum(float v) {
#pragma unroll
    for (int off = 16; off > 0; off >>= 1) v += __shfl_xor(v, off, 32);
    return v;
}
__device__ __forceinline__ float quarter_sum(float v) {
#pragma unroll
    for (int off = 8; off > 0; off >>= 1) v += __shfl_xor(v, off, 16);
    return v;
}

__device__ __forceinline__ float bf2f(u16 h) {
    union { unsigned u; float f; } x;
    x.u = ((unsigned)h) << 16;
    return x.f;
}
__device__ __forceinline__ float bflo(unsigned u) { return bf2f((u16)(u & 0xffff)); }
__device__ __forceinline__ float bfhi(unsigned u) { return bf2f((u16)(u >> 16)); }
__device__ __forceinline__ u16 f2bf(float f) {  // round-to-nearest-even
    union { float f; unsigned u; } x;
    x.f = f;
    unsigned u = x.u;
    return (u16)((u + 0x7fff + ((u >> 16) & 1)) >> 16);
}
__device__ __forceinline__ unsigned pack2(float a, float b) {
    return (unsigned)f2bf(a) | ((unsigned)f2bf(b) << 16);
}

// ===========================================================================
// K1: fp32 table -> bf16 SLICE-MAJOR layout. Slice s (32 channels) of row v
// lives at dst[(s*V + v)*32 ...], contiguous 3.2MB per slice.
// ===========================================================================
__global__ void table_to_bf16_s(const float* __restrict__ src,
                                u16* __restrict__ dst, int V) {
    int i = blockIdx.x * blockDim.x + threadIdx.x;  // over V*64 channel-pairs
    if (i < V * 64) {
        int v = i >> 6;
        int c2 = i & 63;  // channel pair index, ch = 2*c2
        float a = src[(long)v * D + 2 * c2];
        float b = src[(long)v * D + 2 * c2 + 1];
        int s = c2 >> 4;       // slice
        int p = c2 & 15;       // pair within slice
        *(unsigned*)(dst + ((long)s * V + v) * 32 + 2 * p) = pack2(a, b);
    }
}

// ===========================================================================
// K2 (x4): one slice pass. Quarter-wave (16 lanes) owns a row; lane loads
// uint (2 channels) from the L2-resident 3.2MB slice. Gathers k (norm partial)
// and v (store vb slice-major). kb never stored: dots come via linearity.
// pass==0 initializes knp; pass==3 finishes sqrt -> knp holds knorms.
// ===========================================================================
template <int L>  // L == 20
__global__ void kv_slice_pass(const u16* __restrict__ tslice,
                              const int* __restrict__ kids,
                              const int* __restrict__ vids, int N,
                              u16* __restrict__ vb_slice,
                              float* __restrict__ knp, int pass) {
    const int lane = threadIdx.x & 63;
    const int q = lane >> 4;   // row within group
    const int ql = lane & 15;  // lane within quarter: channel pair 2*ql
    int gw = (int)((blockIdx.x * blockDim.x + threadIdx.x) >> 6);
    int nw = (int)((gridDim.x * blockDim.x) >> 6);
    const int ngroup = N >> 2;
    for (int g = gw; g < ngroup; g += nw) {
        const long ibase = (long)g * (4 * L);
        int kidA = kids[ibase + lane];
        int vidA = vids[ibase + lane];
        int kidB = (lane < 4 * L - 64) ? kids[ibase + 64 + lane] : 0;
        int vidB = (lane < 4 * L - 64) ? vids[ibase + 64 + lane] : 0;
        float k0 = 0.f, k1 = 0.f, v0 = 0.f, v1 = 0.f;
#pragma unroll
        for (int t = 0; t < L; ++t) {
            const int j = L * q + t;
            const int jb = j - 64;
            int kA = __shfl(kidA, j & 63, 64);
            int kB = __shfl(kidB, jb < 0 ? 0 : jb, 64);
            int vA = __shfl(vidA, j & 63, 64);
            int vB = __shfl(vidB, jb < 0 ? 0 : jb, 64);
            const int kj = (j < 64) ? kA : kB;
            const int vj = (j < 64) ? vA : vB;
            const unsigned ke = *(const unsigned*)(tslice + (long)kj * 32 + 2 * ql);
            const unsigned ve = *(const unsigned*)(tslice + (long)vj * 32 + 2 * ql);
            k0 += bflo(ke); k1 += bfhi(ke);
            v0 += bflo(ve); v1 += bfhi(ve);
        }
        const int row = 4 * g + q;
        *(unsigned*)(vb_slice + (long)row * 32 + 2 * ql) = pack2(v0, v1);
        float sq = quarter_sum(k0 * k0 + k1 * k1);
        if (ql == 0) {
            if (pass == 0) knp[row] = sq;
            else if (pass == 3) knp[row] = sqrtf(knp[row] + sq);
            else knp[row] += sq;
        }
    }
}

// ===========================================================================
// A2: s[v] = T16[v] . q_plus (slice-major read; lane covers ch 2*lane,2*lane+1)
// ===========================================================================
__global__ void a2_s(const u16* __restrict__ tbl_s, const float* __restrict__ st,
                     float* __restrict__ s, int V) {
    const int lane = threadIdx.x & 63;
    const int q = lane >> 4;
    const int ql = lane & 15;
    const float2 qp2 = *(const float2*)(st + 128 + 2 * lane);
    int gw = (int)((blockIdx.x * blockDim.x + threadIdx.x) >> 6);
    int nw = (int)((gridDim.x * blockDim.x) >> 6);
    for (int v = gw; v < V; v += nw) {
        const unsigned u = *(const unsigned*)(tbl_s + ((long)q * V + v) * 32 + 2 * ql);
        float d = bflo(u) * qp2.x + bfhi(u) * qp2.y;
        d = wave_sum(d);
        if (lane == 0) s[v] = d;
    }
}

// ===========================================================================
// B2: per row: dot = sum_t s[kid], e = exp(dot/(knorm*|qp|)), store e[row],
// block-reduce esum -> st[386]. No scatter (r8 lesson).
// ===========================================================================
__global__ void b2e(const float* __restrict__ s, const int* __restrict__ kids,
                    const float* __restrict__ knorms, const float* __restrict__ st,
                    float* __restrict__ e, int N) {
    __shared__ float se[4];
    const int tid = threadIdx.x;
    const int row = blockIdx.x * blockDim.x + tid;
    const float qpn = st[385];
    float ev = 0.f;
    if (row < N) {
        const int4* kp = (const int4*)(kids + (long)row * 20);
        int4 k0 = kp[0], k1 = kp[1], k2 = kp[2], k3 = kp[3], k4 = kp[4];
        float dot = s[k0.x] + s[k0.y] + s[k0.z] + s[k0.w] +
                    s[k1.x] + s[k1.y] + s[k1.z] + s[k1.w] +
                    s[k2.x] + s[k2.y] + s[k2.z] + s[k2.w] +
                    s[k3.x] + s[k3.y] + s[k3.z] + s[k3.w] +
                    s[k4.x] + s[k4.y] + s[k4.z] + s[k4.w];
        const float c = dot / fmaxf(knorms[row] * qpn, EPS);
        ev = __expf(c);
        e[row] = ev;
    }
    float et = wave_sum(ev);
    if ((tid & 63) == 0) se[tid >> 6] = et;
    __syncthreads();
    if (tid == 0) atomicAdd((float*)&st[386], se[0] + se[1] + se[2] + se[3]);
}

// ===========================================================================
// CV: st[256..383] += sum_i e[i] * vb16[i]. Half-wave per row; lane hl reads
// 8B of slice hl>>3 (slice-major). GRID MUST BE <=1024 BLOCKS (r10 lesson:
// per-block global atomics into st[] serialize; 8192 blocks cost 266us).
// ===========================================================================
__global__ void cv_acc(const u16* __restrict__ vb, const float* __restrict__ e,
                       float* __restrict__ st, int N) {
    __shared__ float acc_s[128];
    const int tid = threadIdx.x;
    const int lane = tid & 63;
    const int half = lane >> 5;
    const int hl = lane & 31;
    const int s4 = hl >> 3;
    const int w8 = hl & 7;
    int gw = (int)((blockIdx.x * blockDim.x + tid) >> 6);
    int nw = (int)((gridDim.x * blockDim.x) >> 6);
    float4 acc = {0.f, 0.f, 0.f, 0.f};
    const int npair = N >> 1;
    for (int p = gw; p < npair; p += nw) {
        const int i = 2 * p + half;
        float ei = e[i];  // same per half-wave (L2/L1 broadcast)
        const ushort4 vh = *(const ushort4*)(vb + ((long)s4 * N + i) * 32 + 4 * w8);
        acc.x += ei * bf2f(vh.x);
        acc.y += ei * bf2f(vh.y);
        acc.z += ei * bf2f(vh.z);
        acc.w += ei * bf2f(vh.w);
    }
    // merge halves (identical channel mapping)
    acc.x += __shfl_xor(acc.x, 32, 64);
    acc.y += __shfl_xor(acc.y, 32, 64);
    acc.z += __shfl_xor(acc.z, 32, 64);
    acc.w += __shfl_xor(acc.w, 32, 64);
    if (tid < 128) acc_s[tid] = 0.f;
    __syncthreads();
    const int ch = 32 * s4 + 4 * w8;
    if (half == 0) {
        atomicAdd(&acc_s[ch + 0], acc.x);
        atomicAdd(&acc_s[ch + 1], acc.y);
        atomicAdd(&acc_s[ch + 2], acc.z);
        atomicAdd(&acc_s[ch + 3], acc.w);
    }
    __syncthreads();
    if (tid < 128) atomicAdd(&st[256 + tid], acc_s[tid]);
}

// ===========================================================================
// Small fp32 encodes: persona rows + q, one block.
// ===========================================================================
__global__ void encode_small(const float* __restrict__ emb,
                             const int* __restrict__ pers, int NP, int LP,
                             const int* __restrict__ xs, int LQ,
                             float* __restrict__ pers_rows,
                             float* __restrict__ pnorms,
                             float* __restrict__ st) {
    int lane = threadIdx.x & 63;
    int w = threadIdx.x >> 6;
    for (int i = w; i <= NP; i += 4) {
        const int* ids;
        int L;
        float* out;
        float* nrm;
        if (i < NP) { ids = pers + (long)i * LP; L = LP; out = pers_rows + (long)i * D; nrm = pnorms + i; }
        else        { ids = xs; L = LQ; out = st; nrm = st + 384; }
        float2 acc = {0.f, 0.f};
        for (int t = 0; t < L; ++t) {
            int idx = ids[t];
            const float2 e = *(const float2*)(emb + (long)idx * D + 2 * lane);
            acc.x += e.x;
            acc.y += e.y;
        }
        *(float2*)(out + 2 * lane) = acc;
        float sq = wave_sum(acc.x * acc.x + acc.y * acc.y);
        if (lane == 0) *nrm = sqrtf(sq);
    }
}

// ===========================================================================
// Hop kernels (1 block, 128 threads) — known-good since r3.
// ===========================================================================
__global__ void persona_hop(const float* __restrict__ pers_rows,
                            const float* __restrict__ pnorms,
                            const float* __restrict__ W,
                            float* __restrict__ st, int NP) {
    __shared__ float qsh[D];
    __shared__ float att[64];
    __shared__ float qh[D];
    __shared__ float red[2];
    int tid = threadIdx.x;
    qsh[tid] = st[tid];
    __syncthreads();
    if (tid < NP) {
        float dot = 0.f;
        for (int d2 = 0; d2 < D; ++d2) dot += pers_rows[tid * D + d2] * qsh[d2];
        att[tid] = dot / fmaxf(pnorms[tid] * st[384], EPS);
    }
    __syncthreads();
    if (tid == 0) {
        float m = -1e30f;
        for (int p = 0; p < NP; ++p) m = fmaxf(m, att[p]);
        float s = 0.f;
        for (int p = 0; p < NP; ++p) { att[p] = __expf(att[p] - m); s += att[p]; }
        float inv = 1.f / s;
        for (int p = 0; p < NP; ++p) att[p] *= inv;
    }
    __syncthreads();
    float h = 0.f;
    for (int p = 0; p < NP; ++p) h += att[p] * pers_rows[p * D + tid];
    qh[tid] = qsh[tid] + h;
    __syncthreads();
    float qp = 0.f;
    for (int d2 = 0; d2 < D; ++d2) qp += W[tid * D + d2] * qh[d2];
    st[128 + tid] = qp;
    float sq = wave_sum(qp * qp);
    if ((tid & 63) == 0) red[tid >> 6] = sq;
    __syncthreads();
    if (tid == 0) st[385] = sqrtf(red[0] + red[1]);
    st[256 + tid] = 0.f;
    if (tid == 0) st[386] = 0.f;
}

__global__ void mid_hop(const float* __restrict__ W1, const float* __restrict__ W2,
                        const float* __restrict__ pers_rows,
                        const float* __restrict__ pnorms,
                        float* __restrict__ st, int NP) {
    __shared__ float qh[D];
    __shared__ float qsh[D];
    __shared__ float att[64];
    __shared__ float red[2];
    int tid = threadIdx.x;
    float inv = 1.f / st[386];
    qh[tid] = st[128 + tid] + st[256 + tid] * inv;
    __syncthreads();
    float qn = 0.f;
    for (int d2 = 0; d2 < D; ++d2) qn += W1[tid * D + d2] * qh[d2];
    qsh[tid] = qn;
    st[tid] = qn;
    float sq = wave_sum(qn * qn);
    if ((tid & 63) == 0) red[tid >> 6] = sq;
    __syncthreads();
    float qnorm = sqrtf(red[0] + red[1]);
    if (tid == 0) st[384] = qnorm;
    if (tid < NP) {
        float dot = 0.f;
        for (int d2 = 0; d2 < D; ++d2) dot += pers_rows[tid * D + d2] * qsh[d2];
        att[tid] = dot / fmaxf(pnorms[tid] * qnorm, EPS);
    }
    __syncthreads();
    if (tid == 0) {
        float m = -1e30f;
        for (int p = 0; p < NP; ++p) m = fmaxf(m, att[p]);
        float s = 0.f;
        for (int p = 0; p < NP; ++p) { att[p] = __expf(att[p] - m); s += att[p]; }
        float is = 1.f / s;
        for (int p = 0; p < NP; ++p) att[p] *= is;
    }
    __syncthreads();
    float h = 0.f;
    for (int p = 0; p < NP; ++p) h += att[p] * pers_rows[p * D + tid];
    qh[tid] = qsh[tid] + h;
    __syncthreads();
    float qp = 0.f;
    for (int d2 = 0; d2 < D; ++d2) qp += W2[tid * D + d2] * qh[d2];
    st[128 + tid] = qp;
    float sq2 = wave_sum(qp * qp);
    if ((tid & 63) == 0) red[tid >> 6] = sq2;
    __syncthreads();
    if (tid == 0) st[385] = sqrtf(red[0] + red[1]);
    st[256 + tid] = 0.f;
    if (tid == 0) st[386] = 0.f;
}

__global__ void finish_hop(const float* __restrict__ W, float* __restrict__ st) {
    __shared__ float qh[D];
    __shared__ float red[2];
    int tid = threadIdx.x;
    float inv = 1.f / st[386];
    qh[tid] = st[128 + tid] + st[256 + tid] * inv;
    __syncthreads();
    float qn = 0.f;
    for (int d2 = 0; d2 < D; ++d2) qn += W[tid * D + d2] * qh[d2];
    st[tid] = qn;
    float sq = wave_sum(qn * qn);
    if ((tid & 63) == 0) red[tid >> 6] = sq;
    __syncthreads();
    if (tid == 0) st[384] = sqrtf(red[0] + red[1]);
}

// ===========================================================================
// K5: candidate gather + cosine, fused.
// ===========================================================================
__global__ void k5_final(const float* __restrict__ cemb,
                         const int* __restrict__ cands, int NC,
                         const float* __restrict__ st, float* __restrict__ out) {
    const int lane = threadIdx.x & 63;
    const int half = lane >> 5;
    const int hl = lane & 31;
    const int gw = (int)((blockIdx.x * blockDim.x + threadIdx.x) >> 6);
    const int nw = (int)((gridDim.x * blockDim.x) >> 6);
    const float4 q4 = *(const float4*)(st + 4 * hl);
    const float qn = st[384];
    const int npair = (NC + 1) >> 1;
    for (int p = gw; p < npair; p += nw) {
        const int row = 2 * p + half;
        const bool valid = row < NC;
        const int rowc = valid ? row : (NC - 1);
        int myid = 0;
        if (hl < 20) myid = cands[(long)rowc * 20 + hl];
        float4 acc = {0.f, 0.f, 0.f, 0.f};
#pragma unroll
        for (int t = 0; t < 20; ++t) {
            const int idx = __shfl(myid, (half << 5) + t, 64);
            const float4 e = *(const float4*)(cemb + (long)idx * D + 4 * hl);
            acc.x += e.x; acc.y += e.y; acc.z += e.z; acc.w += e.w;
        }
        float dot = halfwave_sum(acc.x * q4.x + acc.y * q4.y +
                                 acc.z * q4.z + acc.w * q4.w);
        float nsq = halfwave_sum(acc.x * acc.x + acc.y * acc.y +
                                 acc.z * acc.z + acc.w * acc.w);
        if (valid && hl == 0) out[row] = dot / fmaxf(sqrtf(nsq) * qn, EPS);
    }
}

// ===========================================================================
// Fallback big attention: fp32 on-the-fly gather (workspace too small).
// ===========================================================================
__global__ void big_att_rc(const float* __restrict__ emb,
                           const int* __restrict__ kids,
                           const int* __restrict__ vids,
                           float* __restrict__ st, int N) {
    __shared__ float s[129];
    const int tid = threadIdx.x;
    const int lane = tid & 63;
    const int half = lane >> 5;
    const int hl = lane & 31;
    const int gw = (int)((blockIdx.x * blockDim.x + tid) >> 6);
    const int nw = (int)((gridDim.x * blockDim.x) >> 6);
    const float4 qp = *(const float4*)(st + 128 + 4 * hl);
    const float qpn = st[385];
    float4 hacc = {0.f, 0.f, 0.f, 0.f};
    float esum = 0.f;
    const int npair = (N + 1) >> 1;
    for (int p = gw; p < npair; p += nw) {
        const int row = 2 * p + half;
        const bool valid = row < N;
        const int rowc = valid ? row : (N - 1);
        int kid = 0, vid = 0;
        if (hl < 20) {
            kid = kids[(long)rowc * 20 + hl];
            vid = vids[(long)rowc * 20 + hl];
        }
        float4 ka = {0.f, 0.f, 0.f, 0.f}, va = {0.f, 0.f, 0.f, 0.f};
#pragma unroll
        for (int t = 0; t < 20; ++t) {
            const int ki = __shfl(kid, (half << 5) + t, 64);
            const int vi = __shfl(vid, (half << 5) + t, 64);
            const float4 ke = *(const float4*)(emb + (long)ki * D + 4 * hl);
            const float4 ve = *(const float4*)(emb + (long)vi * D + 4 * hl);
            ka.x += ke.x; ka.y += ke.y; ka.z += ke.z; ka.w += ke.w;
            va.x += ve.x; va.y += ve.y; va.z += ve.z; va.w += ve.w;
        }
        float nsq = halfwave_sum(ka.x * ka.x + ka.y * ka.y + ka.z * ka.z + ka.w * ka.w);
        float dot = halfwave_sum(ka.x * qp.x + ka.y * qp.y + ka.z * qp.z + ka.w * qp.w);
        const float c = dot / fmaxf(sqrtf(nsq) * qpn, EPS);
        float e = __expf(c);
        if (!valid) e = 0.f;
        hacc.x += e * va.x; hacc.y += e * va.y;
        hacc.z += e * va.z; hacc.w += e * va.w;
        if (hl == 0) esum += e;
    }
    hacc.x += __shfl_xor(hacc.x, 32, 64);
    hacc.y += __shfl_xor(hacc.y, 32, 64);
    hacc.z += __shfl_xor(hacc.z, 32, 64);
    hacc.w += __shfl_xor(hacc.w, 32, 64);
    esum += __shfl_xor(esum, 32, 64);
    if (tid < 129) s[tid] = 0.f;
    __syncthreads();
    if (half == 0) {
        atomicAdd(&s[4 * hl + 0], hacc.x);
        atomicAdd(&s[4 * hl + 1], hacc.y);
        atomicAdd(&s[4 * hl + 2], hacc.z);
        atomicAdd(&s[4 * hl + 3], hacc.w);
        if (hl == 0) atomicAdd(&s[128], esum);
    }
    __syncthreads();
    if (tid < 128) atomicAdd(&st[256 + tid], s[tid]);
    if (tid == 128) atomicAdd(&st[386], s[128]);
}

static inline size_t align16(size_t b) { return (b + 15) & ~(size_t)15; }

extern "C" void kernel_launch(void* const* d_in, const int* in_sizes, int n_in,
                              void* d_out, int out_size, void* d_ws, size_t ws_size,
                              hipStream_t stream) {
    const int* xs = (const int*)d_in[0];
    const int* cands = (const int*)d_in[1];
    const int* pers = (const int*)d_in[2];
    const int* keys = (const int*)d_in[3];
    const int* values = (const int*)d_in[4];
    const float* semb = (const float*)d_in[6];
    const float* cemb = (const float*)d_in[7];
    const float* RW = (const float*)d_in[8];
    const float* R2W = (const float*)d_in[9];
    float* out = (float*)d_out;

    const int L = 20;
    const int LQ = in_sizes[0];
    const int VD = in_sizes[6];         // V*D
    const int V = VD / D;               // 50000
    const int NMEM = in_sizes[3] / L;   // 65536
    const int NCAND = in_sizes[1] / L;  // 10000
    const int NPERS = in_sizes[2] / L;  // 20

    size_t need = align16((size_t)VD * 2) + align16((size_t)NMEM * D * 2) +
                  align16((size_t)NMEM * 4) * 2 + align16((size_t)V * 4) +
                  align16((size_t)NPERS * D * 4) + align16((size_t)NPERS * 4) +
                  512 * 4;
    bool stored = (d_ws != nullptr) && (ws_size >= need) && (NMEM % 4 == 0) &&
                  ((VD & 3) == 0);

    const int THR = 256;
    char* base = (char*)d_ws;
    u16 *tbl16s = nullptr, *vb = nullptr;
    float *knp = nullptr, *sv = nullptr, *ev = nullptr;
    if (stored) {
        tbl16s = (u16*)base; base += align16((size_t)VD * 2);        // slice-major
        vb = (u16*)base;     base += align16((size_t)NMEM * D * 2);  // slice-major
        knp = (float*)base;  base += align16((size_t)NMEM * 4);      // -> knorms
        ev = (float*)base;   base += align16((size_t)NMEM * 4);
        sv = (float*)base;   base += align16((size_t)V * 4);
    }
    float* enc_pers = (float*)base; base += align16((size_t)NPERS * D * 4);
    float* pnorms = (float*)base;   base += align16((size_t)NPERS * 4);
    float* st = (float*)base;

    if (stored) {
        // K1: slice-major bf16 conversion
        {
            int n = V * 64;
            table_to_bf16_s<<<(n + THR - 1) / THR, THR, 0, stream>>>(semb, tbl16s, V);
        }
        // K2 x4: slice passes (gather k->norm partials, v->vb; L2-resident slice)
        {
            int ngroup = NMEM / 4;          // 1 group per wave
            int blocks = (ngroup + 3) / 4;  // 4 waves/block
            for (int s = 0; s < 4; ++s) {
                kv_slice_pass<20><<<blocks, THR, 0, stream>>>(
                    tbl16s + (size_t)s * V * 32, keys, values, NMEM,
                    vb + (size_t)s * NMEM * 32, knp, s);
            }
        }
        // small encodes + persona hop 1 (zeroes acc/esum)
        encode_small<<<1, THR, 0, stream>>>(semb, pers, NPERS, L, xs, LQ,
                                            enc_pers, pnorms, st);
        persona_hop<<<1, 128, 0, stream>>>(enc_pers, pnorms, RW, st, NPERS);
        // hop 1: s = T.q_plus ; e per row ; acc += e*v
        a2_s<<<2048, THR, 0, stream>>>(tbl16s, st, sv, V);
        b2e<<<NMEM / THR, THR, 0, stream>>>(sv, keys, knp, st, ev, NMEM);
        cv_acc<<<1024, THR, 0, stream>>>(vb, ev, st, NMEM);   // <=1024 (r10!)
        mid_hop<<<1, 128, 0, stream>>>(RW, R2W, enc_pers, pnorms, st, NPERS);
        // hop 2
        a2_s<<<2048, THR, 0, stream>>>(tbl16s, st, sv, V);
        b2e<<<NMEM / THR, THR, 0, stream>>>(sv, keys, knp, st, ev, NMEM);
        cv_acc<<<1024, THR, 0, stream>>>(vb, ev, st, NMEM);   // <=1024 (r10!)
        finish_hop<<<1, 128, 0, stream>>>(R2W, st);
        // final: fused candidate gather + cosine
        int nblk5 = (((NCAND + 1) / 2) + 3) / 4;
        k5_final<<<nblk5, THR, 0, stream>>>(cemb, cands, NCAND, st, out);
        (void)n_in; (void)out_size;
        return;
    }

    // -------- fallback: fp32 on-the-fly gather --------
    encode_small<<<1, THR, 0, stream>>>(semb, pers, NPERS, L, xs, LQ,
                                        enc_pers, pnorms, st);
    persona_hop<<<1, 128, 0, stream>>>(enc_pers, pnorms, RW, st, NPERS);
    big_att_rc<<<1024, THR, 0, stream>>>(semb, keys, values, st, NMEM);
    mid_hop<<<1, 128, 0, stream>>>(RW, R2W, enc_pers, pnorms, st, NPERS);
    big_att_rc<<<1024, THR, 0, stream>>>(semb, keys, values, st, NMEM);
    finish_hop<<<1, 128, 0, stream>>>(R2W, st);
    int nblk5 = (((NCAND + 1) / 2) + 3) / 4;
    k5_final<<<nblk5, THR, 0, stream>>>(cemb, cands, NCAND, st, out);

    (void)n_in; (void)out_size;
}

// Round 12
// 339.418 us; speedup vs baseline: 2.5067x; 1.1419x over previous
//
#include <hip/hip_runtime.h>
#include <math.h>
#include <stdint.h>

#define D 128
#define EPS 1e-6f
typedef unsigned short u16;

// ---------------------------------------------------------------------------
// state layout (floats), 16B-aligned base:
//   st[0..127]   : q
//   st[128..255] : q_plus
//   st[256..383] : hop accumulator (device atomicAdd targets)
//   st[384]      : ||q||   st[385] : ||q_plus||   st[386] : sum-of-exp
// Rules learned: no device fences after bulk writes (r6, ~100us); no global
// atomic scatters (r8, ~84ns/atomic); gather time ~= TCC bytes / 3.8 TB/s
// (r9); reducer grids <= 1024 blocks (r10); single-block serial gathers are
// ~60us latency traps — always preload ids + pair-encode (r11).
// ---------------------------------------------------------------------------

__device__ __forceinline__ float wave_sum(float v) {
#pragma unroll
    for (int off = 32; off > 0; off >>= 1) v += __shfl_xor(v, off, 64);
    return v;
}
__device__ __forceinline__ float halfwave_sum(float v) {
#pragma unroll
    for (int off = 16; off > 0; off >>= 1) v += __shfl_xor(v, off, 32);
    return v;
}
__device__ __forceinline__ float quarter_sum(float v) {
#pragma unroll
    for (int off = 8; off > 0; off >>= 1) v += __shfl_xor(v, off, 16);
    return v;
}

__device__ __forceinline__ float bf2f(u16 h) {
    union { unsigned u; float f; } x;
    x.u = ((unsigned)h) << 16;
    return x.f;
}
__device__ __forceinline__ float bflo(unsigned u) { return bf2f((u16)(u & 0xffff)); }
__device__ __forceinline__ float bfhi(unsigned u) { return bf2f((u16)(u >> 16)); }
__device__ __forceinline__ u16 f2bf(float f) {  // round-to-nearest-even
    union { float f; unsigned u; } x;
    x.f = f;
    unsigned u = x.u;
    return (u16)((u + 0x7fff + ((u >> 16) & 1)) >> 16);
}
__device__ __forceinline__ unsigned pack2(float a, float b) {
    return (unsigned)f2bf(a) | ((unsigned)f2bf(b) << 16);
}

// ===========================================================================
// K1: fp32 table -> bf16 SLICE-MAJOR layout. Slice s (32 channels) of row v
// lives at dst[(s*V + v)*32 ...], contiguous 3.2MB per slice.
// ===========================================================================
__global__ void table_to_bf16_s(const float* __restrict__ src,
                                u16* __restrict__ dst, int V) {
    int i = blockIdx.x * blockDim.x + threadIdx.x;  // over V*64 channel-pairs
    if (i < V * 64) {
        int v = i >> 6;
        int c2 = i & 63;  // channel pair index, ch = 2*c2
        float a = src[(long)v * D + 2 * c2];
        float b = src[(long)v * D + 2 * c2 + 1];
        int s = c2 >> 4;       // slice
        int p = c2 & 15;       // pair within slice
        *(unsigned*)(dst + ((long)s * V + v) * 32 + 2 * p) = pack2(a, b);
    }
}

// ===========================================================================
// K2 (x4): one slice pass. Quarter-wave (16 lanes) owns a row; lane loads
// uint (2 channels) from the L2-resident 3.2MB slice. Gathers k (norm partial)
// and v (store vb slice-major). kb never stored: dots come via linearity.
// pass==0 initializes knp; pass==3 finishes sqrt -> knp holds knorms.
// ===========================================================================
template <int L>  // L == 20
__global__ void kv_slice_pass(const u16* __restrict__ tslice,
                              const int* __restrict__ kids,
                              const int* __restrict__ vids, int N,
                              u16* __restrict__ vb_slice,
                              float* __restrict__ knp, int pass) {
    const int lane = threadIdx.x & 63;
    const int q = lane >> 4;   // row within group
    const int ql = lane & 15;  // lane within quarter: channel pair 2*ql
    int gw = (int)((blockIdx.x * blockDim.x + threadIdx.x) >> 6);
    int nw = (int)((gridDim.x * blockDim.x) >> 6);
    const int ngroup = N >> 2;
    for (int g = gw; g < ngroup; g += nw) {
        const long ibase = (long)g * (4 * L);
        int kidA = kids[ibase + lane];
        int vidA = vids[ibase + lane];
        int kidB = (lane < 4 * L - 64) ? kids[ibase + 64 + lane] : 0;
        int vidB = (lane < 4 * L - 64) ? vids[ibase + 64 + lane] : 0;
        float k0 = 0.f, k1 = 0.f, v0 = 0.f, v1 = 0.f;
#pragma unroll
        for (int t = 0; t < L; ++t) {
            const int j = L * q + t;
            const int jb = j - 64;
            int kA = __shfl(kidA, j & 63, 64);
            int kB = __shfl(kidB, jb < 0 ? 0 : jb, 64);
            int vA = __shfl(vidA, j & 63, 64);
            int vB = __shfl(vidB, jb < 0 ? 0 : jb, 64);
            const int kj = (j < 64) ? kA : kB;
            const int vj = (j < 64) ? vA : vB;
            const unsigned ke = *(const unsigned*)(tslice + (long)kj * 32 + 2 * ql);
            const unsigned ve = *(const unsigned*)(tslice + (long)vj * 32 + 2 * ql);
            k0 += bflo(ke); k1 += bfhi(ke);
            v0 += bflo(ve); v1 += bfhi(ve);
        }
        const int row = 4 * g + q;
        *(unsigned*)(vb_slice + (long)row * 32 + 2 * ql) = pack2(v0, v1);
        float sq = quarter_sum(k0 * k0 + k1 * k1);
        if (ql == 0) {
            if (pass == 0) knp[row] = sq;
            else if (pass == 3) knp[row] = sqrtf(knp[row] + sq);
            else knp[row] += sq;
        }
    }
}

// ===========================================================================
// A2: s[v] = T16[v] . q_plus (slice-major read; lane covers ch 2*lane,2*lane+1)
// ===========================================================================
__global__ void a2_s(const u16* __restrict__ tbl_s, const float* __restrict__ st,
                     float* __restrict__ s, int V) {
    const int lane = threadIdx.x & 63;
    const int q = lane >> 4;
    const int ql = lane & 15;
    const float2 qp2 = *(const float2*)(st + 128 + 2 * lane);
    int gw = (int)((blockIdx.x * blockDim.x + threadIdx.x) >> 6);
    int nw = (int)((gridDim.x * blockDim.x) >> 6);
    for (int v = gw; v < V; v += nw) {
        const unsigned u = *(const unsigned*)(tbl_s + ((long)q * V + v) * 32 + 2 * ql);
        float d = bflo(u) * qp2.x + bfhi(u) * qp2.y;
        d = wave_sum(d);
        if (lane == 0) s[v] = d;
    }
}

// ===========================================================================
// B2: per row: dot = sum_t s[kid], e = exp(dot/(knorm*|qp|)), store e[row],
// block-reduce esum -> st[386]. No scatter (r8 lesson).
// ===========================================================================
__global__ void b2e(const float* __restrict__ s, const int* __restrict__ kids,
                    const float* __restrict__ knorms, const float* __restrict__ st,
                    float* __restrict__ e, int N) {
    __shared__ float se[4];
    const int tid = threadIdx.x;
    const int row = blockIdx.x * blockDim.x + tid;
    const float qpn = st[385];
    float ev = 0.f;
    if (row < N) {
        const int4* kp = (const int4*)(kids + (long)row * 20);
        int4 k0 = kp[0], k1 = kp[1], k2 = kp[2], k3 = kp[3], k4 = kp[4];
        float dot = s[k0.x] + s[k0.y] + s[k0.z] + s[k0.w] +
                    s[k1.x] + s[k1.y] + s[k1.z] + s[k1.w] +
                    s[k2.x] + s[k2.y] + s[k2.z] + s[k2.w] +
                    s[k3.x] + s[k3.y] + s[k3.z] + s[k3.w] +
                    s[k4.x] + s[k4.y] + s[k4.z] + s[k4.w];
        const float c = dot / fmaxf(knorms[row] * qpn, EPS);
        ev = __expf(c);
        e[row] = ev;
    }
    float et = wave_sum(ev);
    if ((tid & 63) == 0) se[tid >> 6] = et;
    __syncthreads();
    if (tid == 0) atomicAdd((float*)&st[386], se[0] + se[1] + se[2] + se[3]);
}

// ===========================================================================
// CV: st[256..383] += sum_i e[i] * vb16[i]. Half-wave per row; lane hl reads
// 8B of slice hl>>3 (slice-major). GRID <=1024 BLOCKS (r10 lesson).
// ===========================================================================
__global__ void cv_acc(const u16* __restrict__ vb, const float* __restrict__ e,
                       float* __restrict__ st, int N) {
    __shared__ float acc_s[128];
    const int tid = threadIdx.x;
    const int lane = tid & 63;
    const int half = lane >> 5;
    const int hl = lane & 31;
    const int s4 = hl >> 3;
    const int w8 = hl & 7;
    int gw = (int)((blockIdx.x * blockDim.x + tid) >> 6);
    int nw = (int)((gridDim.x * blockDim.x) >> 6);
    float4 acc = {0.f, 0.f, 0.f, 0.f};
    const int npair = N >> 1;
    for (int p = gw; p < npair; p += nw) {
        const int i = 2 * p + half;
        float ei = e[i];
        const ushort4 vh = *(const ushort4*)(vb + ((long)s4 * N + i) * 32 + 4 * w8);
        acc.x += ei * bf2f(vh.x);
        acc.y += ei * bf2f(vh.y);
        acc.z += ei * bf2f(vh.z);
        acc.w += ei * bf2f(vh.w);
    }
    acc.x += __shfl_xor(acc.x, 32, 64);
    acc.y += __shfl_xor(acc.y, 32, 64);
    acc.z += __shfl_xor(acc.z, 32, 64);
    acc.w += __shfl_xor(acc.w, 32, 64);
    if (tid < 128) acc_s[tid] = 0.f;
    __syncthreads();
    const int ch = 32 * s4 + 4 * w8;
    if (half == 0) {
        atomicAdd(&acc_s[ch + 0], acc.x);
        atomicAdd(&acc_s[ch + 1], acc.y);
        atomicAdd(&acc_s[ch + 2], acc.z);
        atomicAdd(&acc_s[ch + 3], acc.w);
    }
    __syncthreads();
    if (tid < 128) atomicAdd(&st[256 + tid], acc_s[tid]);
}

// ===========================================================================
// Parallel small encode (r12): persona rows + q, pair scheme. 2 rows/wave,
// half-wave float4, ids preloaded + shfl broadcast -> all loads in flight.
// Row NP is the virtual q row (L = LQ <= 32). 21 rows -> 11 pairs -> 3 blocks.
// ===========================================================================
__global__ void encode_small_p(const float* __restrict__ emb,
                               const int* __restrict__ pers, int NP, int LP,
                               const int* __restrict__ xs, int LQ,
                               float* __restrict__ pers_rows,
                               float* __restrict__ pnorms,
                               float* __restrict__ st) {
    const int lane = threadIdx.x & 63;
    const int half = lane >> 5;
    const int hl = lane & 31;
    int gw = (int)((blockIdx.x * blockDim.x + threadIdx.x) >> 6);
    int nw = (int)((gridDim.x * blockDim.x) >> 6);
    const int npr = NP + 1;  // +1 virtual row = q
    const int npairs = (npr + 1) >> 1;
    for (int p = gw; p < npairs; p += nw) {
        const int row = 2 * p + half;
        const bool valid = row < npr;
        const int rowc = valid ? row : NP;  // clamp to q slot (always valid)
        const bool isq = (rowc == NP);
        const int* ids = isq ? xs : (pers + (long)rowc * LP);
        const int L = isq ? LQ : LP;
        int myid = 0;
        if (hl < L) myid = ids[hl];
        float4 acc = {0.f, 0.f, 0.f, 0.f};
        for (int t = 0; t < L; ++t) {
            const int idx = __shfl(myid, (half << 5) + t, 64);
            const float4 e = *(const float4*)(emb + (long)idx * D + 4 * hl);
            acc.x += e.x; acc.y += e.y; acc.z += e.z; acc.w += e.w;
        }
        if (valid) {
            float* outp = isq ? st : (pers_rows + (long)rowc * D);
            *(float4*)(outp + 4 * hl) = acc;
            float sq = acc.x * acc.x + acc.y * acc.y + acc.z * acc.z + acc.w * acc.w;
            sq = halfwave_sum(sq);
            if (hl == 0) {
                if (isq) st[384] = sqrtf(sq);
                else pnorms[rowc] = sqrtf(sq);
            }
        }
    }
}

// ===========================================================================
// Hop kernels (1 block, 128 threads) — known-good since r3.
// ===========================================================================
__global__ void persona_hop(const float* __restrict__ pers_rows,
                            const float* __restrict__ pnorms,
                            const float* __restrict__ W,
                            float* __restrict__ st, int NP) {
    __shared__ float qsh[D];
    __shared__ float att[64];
    __shared__ float qh[D];
    __shared__ float red[2];
    int tid = threadIdx.x;
    qsh[tid] = st[tid];
    __syncthreads();
    if (tid < NP) {
        float dot = 0.f;
        for (int d2 = 0; d2 < D; ++d2) dot += pers_rows[tid * D + d2] * qsh[d2];
        att[tid] = dot / fmaxf(pnorms[tid] * st[384], EPS);
    }
    __syncthreads();
    if (tid == 0) {
        float m = -1e30f;
        for (int p = 0; p < NP; ++p) m = fmaxf(m, att[p]);
        float s = 0.f;
        for (int p = 0; p < NP; ++p) { att[p] = __expf(att[p] - m); s += att[p]; }
        float inv = 1.f / s;
        for (int p = 0; p < NP; ++p) att[p] *= inv;
    }
    __syncthreads();
    float h = 0.f;
    for (int p = 0; p < NP; ++p) h += att[p] * pers_rows[p * D + tid];
    qh[tid] = qsh[tid] + h;
    __syncthreads();
    float qp = 0.f;
    for (int d2 = 0; d2 < D; ++d2) qp += W[tid * D + d2] * qh[d2];
    st[128 + tid] = qp;
    float sq = wave_sum(qp * qp);
    if ((tid & 63) == 0) red[tid >> 6] = sq;
    __syncthreads();
    if (tid == 0) st[385] = sqrtf(red[0] + red[1]);
    st[256 + tid] = 0.f;
    if (tid == 0) st[386] = 0.f;
}

__global__ void mid_hop(const float* __restrict__ W1, const float* __restrict__ W2,
                        const float* __restrict__ pers_rows,
                        const float* __restrict__ pnorms,
                        float* __restrict__ st, int NP) {
    __shared__ float qh[D];
    __shared__ float qsh[D];
    __shared__ float att[64];
    __shared__ float red[2];
    int tid = threadIdx.x;
    float inv = 1.f / st[386];
    qh[tid] = st[128 + tid] + st[256 + tid] * inv;
    __syncthreads();
    float qn = 0.f;
    for (int d2 = 0; d2 < D; ++d2) qn += W1[tid * D + d2] * qh[d2];
    qsh[tid] = qn;
    st[tid] = qn;
    float sq = wave_sum(qn * qn);
    if ((tid & 63) == 0) red[tid >> 6] = sq;
    __syncthreads();
    float qnorm = sqrtf(red[0] + red[1]);
    if (tid == 0) st[384] = qnorm;
    if (tid < NP) {
        float dot = 0.f;
        for (int d2 = 0; d2 < D; ++d2) dot += pers_rows[tid * D + d2] * qsh[d2];
        att[tid] = dot / fmaxf(pnorms[tid] * qnorm, EPS);
    }
    __syncthreads();
    if (tid == 0) {
        float m = -1e30f;
        for (int p = 0; p < NP; ++p) m = fmaxf(m, att[p]);
        float s = 0.f;
        for (int p = 0; p < NP; ++p) { att[p] = __expf(att[p] - m); s += att[p]; }
        float is = 1.f / s;
        for (int p = 0; p < NP; ++p) att[p] *= is;
    }
    __syncthreads();
    float h = 0.f;
    for (int p = 0; p < NP; ++p) h += att[p] * pers_rows[p * D + tid];
    qh[tid] = qsh[tid] + h;
    __syncthreads();
    float qp = 0.f;
    for (int d2 = 0; d2 < D; ++d2) qp += W2[tid * D + d2] * qh[d2];
    st[128 + tid] = qp;
    float sq2 = wave_sum(qp * qp);
    if ((tid & 63) == 0) red[tid >> 6] = sq2;
    __syncthreads();
    if (tid == 0) st[385] = sqrtf(red[0] + red[1]);
    st[256 + tid] = 0.f;
    if (tid == 0) st[386] = 0.f;
}

__global__ void finish_hop(const float* __restrict__ W, float* __restrict__ st) {
    __shared__ float qh[D];
    __shared__ float red[2];
    int tid = threadIdx.x;
    float inv = 1.f / st[386];
    qh[tid] = st[128 + tid] + st[256 + tid] * inv;
    __syncthreads();
    float qn = 0.f;
    for (int d2 = 0; d2 < D; ++d2) qn += W[tid * D + d2] * qh[d2];
    st[tid] = qn;
    float sq = wave_sum(qn * qn);
    if ((tid & 63) == 0) red[tid >> 6] = sq;
    __syncthreads();
    if (tid == 0) st[384] = sqrtf(red[0] + red[1]);
}

// ===========================================================================
// K5: candidate gather + cosine, fused.
// ===========================================================================
__global__ void k5_final(const float* __restrict__ cemb,
                         const int* __restrict__ cands, int NC,
                         const float* __restrict__ st, float* __restrict__ out) {
    const int lane = threadIdx.x & 63;
    const int half = lane >> 5;
    const int hl = lane & 31;
    const int gw = (int)((blockIdx.x * blockDim.x + threadIdx.x) >> 6);
    const int nw = (int)((gridDim.x * blockDim.x) >> 6);
    const float4 q4 = *(const float4*)(st + 4 * hl);
    const float qn = st[384];
    const int npair = (NC + 1) >> 1;
    for (int p = gw; p < npair; p += nw) {
        const int row = 2 * p + half;
        const bool valid = row < NC;
        const int rowc = valid ? row : (NC - 1);
        int myid = 0;
        if (hl < 20) myid = cands[(long)rowc * 20 + hl];
        float4 acc = {0.f, 0.f, 0.f, 0.f};
#pragma unroll
        for (int t = 0; t < 20; ++t) {
            const int idx = __shfl(myid, (half << 5) + t, 64);
            const float4 e = *(const float4*)(cemb + (long)idx * D + 4 * hl);
            acc.x += e.x; acc.y += e.y; acc.z += e.z; acc.w += e.w;
        }
        float dot = halfwave_sum(acc.x * q4.x + acc.y * q4.y +
                                 acc.z * q4.z + acc.w * q4.w);
        float nsq = halfwave_sum(acc.x * acc.x + acc.y * acc.y +
                                 acc.z * acc.z + acc.w * acc.w);
        if (valid && hl == 0) out[row] = dot / fmaxf(sqrtf(nsq) * qn, EPS);
    }
}

// ===========================================================================
// Fallback big attention: fp32 on-the-fly gather (workspace too small).
// ===========================================================================
__global__ void big_att_rc(const float* __restrict__ emb,
                           const int* __restrict__ kids,
                           const int* __restrict__ vids,
                           float* __restrict__ st, int N) {
    __shared__ float s[129];
    const int tid = threadIdx.x;
    const int lane = tid & 63;
    const int half = lane >> 5;
    const int hl = lane & 31;
    const int gw = (int)((blockIdx.x * blockDim.x + tid) >> 6);
    const int nw = (int)((gridDim.x * blockDim.x) >> 6);
    const float4 qp = *(const float4*)(st + 128 + 4 * hl);
    const float qpn = st[385];
    float4 hacc = {0.f, 0.f, 0.f, 0.f};
    float esum = 0.f;
    const int npair = (N + 1) >> 1;
    for (int p = gw; p < npair; p += nw) {
        const int row = 2 * p + half;
        const bool valid = row < N;
        const int rowc = valid ? row : (N - 1);
        int kid = 0, vid = 0;
        if (hl < 20) {
            kid = kids[(long)rowc * 20 + hl];
            vid = vids[(long)rowc * 20 + hl];
        }
        float4 ka = {0.f, 0.f, 0.f, 0.f}, va = {0.f, 0.f, 0.f, 0.f};
#pragma unroll
        for (int t = 0; t < 20; ++t) {
            const int ki = __shfl(kid, (half << 5) + t, 64);
            const int vi = __shfl(vid, (half << 5) + t, 64);
            const float4 ke = *(const float4*)(emb + (long)ki * D + 4 * hl);
            const float4 ve = *(const float4*)(emb + (long)vi * D + 4 * hl);
            ka.x += ke.x; ka.y += ke.y; ka.z += ke.z; ka.w += ke.w;
            va.x += ve.x; va.y += ve.y; va.z += ve.z; va.w += ve.w;
        }
        float nsq = halfwave_sum(ka.x * ka.x + ka.y * ka.y + ka.z * ka.z + ka.w * ka.w);
        float dot = halfwave_sum(ka.x * qp.x + ka.y * qp.y + ka.z * qp.z + ka.w * qp.w);
        const float c = dot / fmaxf(sqrtf(nsq) * qpn, EPS);
        float e = __expf(c);
        if (!valid) e = 0.f;
        hacc.x += e * va.x; hacc.y += e * va.y;
        hacc.z += e * va.z; hacc.w += e * va.w;
        if (hl == 0) esum += e;
    }
    hacc.x += __shfl_xor(hacc.x, 32, 64);
    hacc.y += __shfl_xor(hacc.y, 32, 64);
    hacc.z += __shfl_xor(hacc.z, 32, 64);
    hacc.w += __shfl_xor(hacc.w, 32, 64);
    esum += __shfl_xor(esum, 32, 64);
    if (tid < 129) s[tid] = 0.f;
    __syncthreads();
    if (half == 0) {
        atomicAdd(&s[4 * hl + 0], hacc.x);
        atomicAdd(&s[4 * hl + 1], hacc.y);
        atomicAdd(&s[4 * hl + 2], hacc.z);
        atomicAdd(&s[4 * hl + 3], hacc.w);
        if (hl == 0) atomicAdd(&s[128], esum);
    }
    __syncthreads();
    if (tid < 128) atomicAdd(&st[256 + tid], s[tid]);
    if (tid == 128) atomicAdd(&st[386], s[128]);
}

static inline size_t align16(size_t b) { return (b + 15) & ~(size_t)15; }

extern "C" void kernel_launch(void* const* d_in, const int* in_sizes, int n_in,
                              void* d_out, int out_size, void* d_ws, size_t ws_size,
                              hipStream_t stream) {
    const int* xs = (const int*)d_in[0];
    const int* cands = (const int*)d_in[1];
    const int* pers = (const int*)d_in[2];
    const int* keys = (const int*)d_in[3];
    const int* values = (const int*)d_in[4];
    const float* semb = (const float*)d_in[6];
    const float* cemb = (const float*)d_in[7];
    const float* RW = (const float*)d_in[8];
    const float* R2W = (const float*)d_in[9];
    float* out = (float*)d_out;

    const int L = 20;
    const int LQ = in_sizes[0];
    const int VD = in_sizes[6];         // V*D
    const int V = VD / D;               // 50000
    const int NMEM = in_sizes[3] / L;   // 65536
    const int NCAND = in_sizes[1] / L;  // 10000
    const int NPERS = in_sizes[2] / L;  // 20

    size_t need = align16((size_t)VD * 2) + align16((size_t)NMEM * D * 2) +
                  align16((size_t)NMEM * 4) * 2 + align16((size_t)V * 4) +
                  align16((size_t)NPERS * D * 4) + align16((size_t)NPERS * 4) +
                  512 * 4;
    bool stored = (d_ws != nullptr) && (ws_size >= need) && (NMEM % 4 == 0) &&
                  ((VD & 3) == 0) && (LQ <= 32);

    const int THR = 256;
    char* base = (char*)d_ws;
    u16 *tbl16s = nullptr, *vb = nullptr;
    float *knp = nullptr, *sv = nullptr, *ev = nullptr;
    if (stored) {
        tbl16s = (u16*)base; base += align16((size_t)VD * 2);        // slice-major
        vb = (u16*)base;     base += align16((size_t)NMEM * D * 2);  // slice-major
        knp = (float*)base;  base += align16((size_t)NMEM * 4);      // -> knorms
        ev = (float*)base;   base += align16((size_t)NMEM * 4);
        sv = (float*)base;   base += align16((size_t)V * 4);
    }
    float* enc_pers = (float*)base; base += align16((size_t)NPERS * D * 4);
    float* pnorms = (float*)base;   base += align16((size_t)NPERS * 4);
    float* st = (float*)base;

    if (stored) {
        // K1: slice-major bf16 conversion
        {
            int n = V * 64;
            table_to_bf16_s<<<(n + THR - 1) / THR, THR, 0, stream>>>(semb, tbl16s, V);
        }
        // K2 x4: slice passes (gather k->norm partials, v->vb; L2-resident slice)
        {
            int ngroup = NMEM / 4;          // 1 group per wave
            int blocks = (ngroup + 3) / 4;  // 4 waves/block
            for (int s = 0; s < 4; ++s) {
                kv_slice_pass<20><<<blocks, THR, 0, stream>>>(
                    tbl16s + (size_t)s * V * 32, keys, values, NMEM,
                    vb + (size_t)s * NMEM * 32, knp, s);
            }
        }
        // small encodes (parallel pair scheme, r12) + persona hop 1
        {
            int npairs = (NPERS + 2) / 2;        // (NP+1 rows) / 2 rounded up
            int blocks = (npairs + 3) / 4;
            encode_small_p<<<blocks, THR, 0, stream>>>(semb, pers, NPERS, L, xs,
                                                       LQ, enc_pers, pnorms, st);
        }
        persona_hop<<<1, 128, 0, stream>>>(enc_pers, pnorms, RW, st, NPERS);
        // hop 1: s = T.q_plus ; e per row ; acc += e*v
        a2_s<<<2048, THR, 0, stream>>>(tbl16s, st, sv, V);
        b2e<<<NMEM / THR, THR, 0, stream>>>(sv, keys, knp, st, ev, NMEM);
        cv_acc<<<1024, THR, 0, stream>>>(vb, ev, st, NMEM);   // <=1024 (r10!)
        mid_hop<<<1, 128, 0, stream>>>(RW, R2W, enc_pers, pnorms, st, NPERS);
        // hop 2
        a2_s<<<2048, THR, 0, stream>>>(tbl16s, st, sv, V);
        b2e<<<NMEM / THR, THR, 0, stream>>>(sv, keys, knp, st, ev, NMEM);
        cv_acc<<<1024, THR, 0, stream>>>(vb, ev, st, NMEM);   // <=1024 (r10!)
        finish_hop<<<1, 128, 0, stream>>>(R2W, st);
        // final: fused candidate gather + cosine
        int nblk5 = (((NCAND + 1) / 2) + 3) / 4;
        k5_final<<<nblk5, THR, 0, stream>>>(cemb, cands, NCAND, st, out);
        (void)n_in; (void)out_size;
        return;
    }

    // -------- fallback: fp32 on-the-fly gather --------
    {
        int npairs = (NPERS + 2) / 2;
        int blocks = (npairs + 3) / 4;
        encode_small_p<<<blocks, THR, 0, stream>>>(semb, pers, NPERS, L, xs,
                                                   LQ, enc_pers, pnorms, st);
    }
    persona_hop<<<1, 128, 0, stream>>>(enc_pers, pnorms, RW, st, NPERS);
    big_att_rc<<<1024, THR, 0, stream>>>(semb, keys, values, st, NMEM);
    mid_hop<<<1, 128, 0, stream>>>(RW, R2W, enc_pers, pnorms, st, NPERS);
    big_att_rc<<<1024, THR, 0, stream>>>(semb, keys, values, st, NMEM);
    finish_hop<<<1, 128, 0, stream>>>(R2W, st);
    int nblk5 = (((NCAND + 1) / 2) + 3) / 4;
    k5_final<<<nblk5, THR, 0, stream>>>(cemb, cands, NCAND, st, out);

    (void)n_in; (void)out_size;
}